// Round 1
// baseline (558.498 us; speedup 1.0000x reference)
//
#include <hip/hip_runtime.h>
#include <hip/hip_bf16.h>
#include <cstdint>
#include <cstddef>

typedef __attribute__((ext_vector_type(8))) short short8;
typedef __attribute__((ext_vector_type(4))) float f32x4;
typedef __attribute__((ext_vector_type(4))) unsigned int u32x4;

#define NDIM 100
#define NSTEP 50
#define HID 128
#define NPATH 8192
#define WSTR 272   // bytes per LDS row (136 bf16): 16B-aligned, (n+g+4ks)%8 uniform -> no bank hotspot
#define XSTR 128   // X row stride (elems): [S/S0 (100), t (1), zeros (27)]
#define QSTR 104   // q row stride (elems)

__device__ __forceinline__ unsigned short f2b(float f){
  unsigned int u = __float_as_uint(f);
  u += 0x7fffu + ((u >> 16) & 1u);          // RNE
  return (unsigned short)(u >> 16);
}
__device__ __forceinline__ float b2f(unsigned short h){
  return __uint_as_float(((unsigned int)h) << 16);
}
__device__ __forceinline__ float frcp(float x){ return __builtin_amdgcn_rcpf(x); }
__device__ __forceinline__ float sigm(float x){ return frcp(1.f + __expf(-x)); }
__device__ __forceinline__ float gelu_fast(float y){ return y * sigm(1.702f * y); }

// ---------------- weight prep: transpose to [n][k] bf16, zero-padded ----------------
// WT layout (elems): WT1 [128n][128k] @0 ; WT2 @16384 ; WT3 @32768 ; WT4 [112n][128k] @49152
__global__ __launch_bounds__(256) void prep_weights(
    const float* __restrict__ W1, const float* __restrict__ W2,
    const float* __restrict__ W3, const float* __restrict__ W4,
    unsigned short* __restrict__ WT)
{
  int idx = blockIdx.x * 256 + threadIdx.x;   // grid covers exactly 63488
  if (idx < 16384){
    int n = idx >> 7, k = idx & 127;
    WT[idx] = (k < 101) ? f2b(W1[k * 128 + n]) : (unsigned short)0;
  } else if (idx < 32768){
    int t = idx - 16384; int n = t >> 7, k = t & 127;
    WT[idx] = f2b(W2[k * 128 + n]);
  } else if (idx < 49152){
    int t = idx - 32768; int n = t >> 7, k = t & 127;
    WT[idx] = f2b(W3[k * 128 + n]);
  } else if (idx < 63488){
    int t = idx - 49152; int n = t >> 7, k = t & 127;
    WT[idx] = (n < 100) ? f2b(W4[k * 100 + n]) : (unsigned short)0;
  }
}

// ---------------- Phase A: S-chain scan, emit X (net input) / q (=P*f) / final S ----------------
__global__ __launch_bounds__(64) void phaseA(
    const float* __restrict__ dw, const float* __restrict__ tg,
    unsigned short* __restrict__ X, unsigned short* __restrict__ q,
    float* __restrict__ Sout, int path0)
{
  const int bl = blockIdx.x;
  const int b  = path0 + bl;
  const int t  = threadIdx.x;
  const int d0 = t, d1 = t + 64;
  float s0 = 100.f, s1 = 100.f;
  const float* dwb = dw + (long)b * NSTEP * NDIM;
  const float* tgb = tg + (long)b * NSTEP;
  unsigned short* Xb = X + (long)bl * NSTEP * XSTR;
  unsigned short* qb = q + (long)bl * NSTEP * QSTR;
  for (int i = 0; i < NSTEP; ++i){
    float tv = tgb[i];
    float w0 = dwb[i * NDIM + d0];
    float w1 = (d1 < NDIM) ? dwb[i * NDIM + d1] : 0.f;
    float f0 = 0.001f + 0.2f * w0;
    float f1 = 0.001f + 0.2f * w1;
    unsigned short* Xr = Xb + i * XSTR;
    unsigned short* qr = qb + i * QSTR;
    float P0 = s0 * 0.01f, P1 = s1 * 0.01f;
    Xr[d0] = f2b(P0);
    qr[d0] = f2b(P0 * f0);
    if (d1 < NDIM){ Xr[d1] = f2b(P1); qr[d1] = f2b(P1 * f1); }
    else if (d1 == NDIM){ Xr[d1] = f2b(tv); }
    else { Xr[d1] = 0; }
    s0 += s0 * f0;
    if (d1 < NDIM) s1 += s1 * f1;
  }
  Sout[(long)b * NDIM + d0] = s0;
  if (d1 < NDIM) Sout[(long)b * NDIM + d1] = s1;
}

// ---------------- Phase B: fused 4-layer MLP over 409600 rows + per-row reduction ----------------
// block = 256 thr = 4 waves; wave owns 64 rows (2 sweeps of 32 = 2 row-tiles of 16).
// MFMA 16x16x32 bf16. A: row=lane&15, k=(lane>>4)*8+j. B: col=lane&15, same k chunking.
// C/D: col=lane&15, row=(lane>>4)*4+reg (m89-verified). Weights transposed in LDS, double-buffered.
__global__ __launch_bounds__(256) void phaseB(
    const unsigned short* __restrict__ X,
    const unsigned short* __restrict__ q,
    const unsigned short* __restrict__ WT,
    const float* __restrict__ b1, const float* __restrict__ g1, const float* __restrict__ be1,
    const float* __restrict__ b2, const float* __restrict__ g2, const float* __restrict__ be2,
    const float* __restrict__ b3, const float* __restrict__ g3, const float* __restrict__ be3,
    const float* __restrict__ b4,
    float* __restrict__ cbuf, long row0)
{
  __shared__ __align__(16) char lds[2 * 34816 + 4 * 17408];   // 139264 B
  char* const wbuf0 = lds;
  char* const wbuf1 = lds + 34816;
  const int tid = threadIdx.x;
  const int w = tid >> 6;
  const int l = tid & 63;
  const int g = l >> 4;
  const int c = l & 15;
  char* const H = lds + 69632 + w * 17408;        // per-wave 64 rows x 272 B
  const long waveRow = (long)blockIdx.x * 256 + w * 64;   // chunk-local first row

  // stage WT1 -> wbuf0
  #pragma unroll
  for (int t = 0; t < 8; ++t){
    int cl = t * 256 + tid;
    *(u32x4*)(wbuf0 + (cl >> 4) * WSTR + (cl & 15) * 16) = *(const u32x4*)(WT + cl * 8);
  }
  __syncthreads();

  u32x4 st[8];
  #pragma unroll
  for (int t = 0; t < 8; ++t) st[t] = *(const u32x4*)(WT + 16384 + (t * 256 + tid) * 8);

  auto write_stage = [&](char* dst){
    #pragma unroll
    for (int t = 0; t < 8; ++t){
      int cl = t * 256 + tid;
      *(u32x4*)(dst + (cl >> 4) * WSTR + (cl & 15) * 16) = st[t];
    }
  };
  auto prefetch = [&](const unsigned short* src){
    #pragma unroll
    for (int t = 0; t < 8; ++t) st[t] = *(const u32x4*)(src + (t * 256 + tid) * 8);
  };
  auto load_afH = [&](int p, short8 (&af)[2][4]){
    #pragma unroll
    for (int rt = 0; rt < 2; ++rt){
      const char* hr = H + (p * 32 + rt * 16 + c) * WSTR + g * 16;
      #pragma unroll
      for (int ks = 0; ks < 4; ++ks) af[rt][ks] = *(const short8*)(hr + ks * 64);
    }
  };

  // dense + LayerNorm + GELU -> H (layers 1..3)
  auto dense_ln = [&](int p, const short8 (&af)[2][4], const char* B,
                      const float* bv, const float* gv, const float* bev){
    f32x4 acc[2][8];
    #pragma unroll
    for (int ct = 0; ct < 8; ++ct){
      f32x4 z; z[0] = bv[ct]; z[1] = bv[ct]; z[2] = bv[ct]; z[3] = bv[ct];
      acc[0][ct] = z; acc[1][ct] = z;
    }
    #pragma unroll
    for (int ct = 0; ct < 8; ++ct){
      short8 bf[4];
      #pragma unroll
      for (int ks = 0; ks < 4; ++ks)
        bf[ks] = *(const short8*)(B + (ct * 16 + c) * WSTR + g * 16 + ks * 64);
      #pragma unroll
      for (int ks = 0; ks < 4; ++ks){
        acc[0][ct] = __builtin_amdgcn_mfma_f32_16x16x32_bf16(af[0][ks], bf[ks], acc[0][ct], 0, 0, 0);
        acc[1][ct] = __builtin_amdgcn_mfma_f32_16x16x32_bf16(af[1][ks], bf[ks], acc[1][ct], 0, 0, 0);
      }
    }
    #pragma unroll
    for (int rt = 0; rt < 2; ++rt){
      #pragma unroll
      for (int j = 0; j < 4; ++j){
        float s1 = 0.f, s2 = 0.f;
        #pragma unroll
        for (int ct = 0; ct < 8; ++ct){ float x = acc[rt][ct][j]; s1 += x; s2 += x * x; }
        s1 += __shfl_xor(s1, 1, 64); s2 += __shfl_xor(s2, 1, 64);
        s1 += __shfl_xor(s1, 2, 64); s2 += __shfl_xor(s2, 2, 64);
        s1 += __shfl_xor(s1, 4, 64); s2 += __shfl_xor(s2, 4, 64);
        s1 += __shfl_xor(s1, 8, 64); s2 += __shfl_xor(s2, 8, 64);
        float mu = s1 * 0.0078125f;
        float var = s2 * 0.0078125f - mu * mu;
        float rstd = rsqrtf(var + 1e-5f);
        int row = p * 32 + rt * 16 + 4 * g + j;
        #pragma unroll
        for (int ct = 0; ct < 8; ++ct){
          float x = acc[rt][ct][j];
          float y = (x - mu) * rstd * gv[ct] + bev[ct];
          float h = gelu_fast(y);
          float other = __shfl_xor(h, 1, 64);       // pack col pairs -> b32 write
          if ((c & 1) == 0){
            unsigned int pk = (unsigned int)f2b(h) | ((unsigned int)f2b(other) << 16);
            *(unsigned int*)(H + row * WSTR + ct * 32 + c * 2) = pk;
          }
        }
      }
    }
  };

  // dense + sigmoid + epilogue reduction -> cbuf (layer 4)
  auto dense_out = [&](int p, const short8 (&af)[2][4], const char* B, const float* bv4){
    f32x4 acc[2][7];
    #pragma unroll
    for (int ct = 0; ct < 7; ++ct){
      f32x4 z; z[0] = bv4[ct]; z[1] = bv4[ct]; z[2] = bv4[ct]; z[3] = bv4[ct];
      acc[0][ct] = z; acc[1][ct] = z;
    }
    #pragma unroll
    for (int ct = 0; ct < 7; ++ct){
      short8 bf[4];
      #pragma unroll
      for (int ks = 0; ks < 4; ++ks)
        bf[ks] = *(const short8*)(B + (ct * 16 + c) * WSTR + g * 16 + ks * 64);
      #pragma unroll
      for (int ks = 0; ks < 4; ++ks){
        acc[0][ct] = __builtin_amdgcn_mfma_f32_16x16x32_bf16(af[0][ks], bf[ks], acc[0][ct], 0, 0, 0);
        acc[1][ct] = __builtin_amdgcn_mfma_f32_16x16x32_bf16(af[1][ks], bf[ks], acc[1][ct], 0, 0, 0);
      }
    }
    #pragma unroll
    for (int rt = 0; rt < 2; ++rt){
      #pragma unroll
      for (int j = 0; j < 4; ++j){
        long rloc = waveRow + p * 32 + rt * 16 + 4 * g + j;
        float pa = 0.f, pg = 0.f;
        #pragma unroll
        for (int ct = 0; ct < 7; ++ct){
          int col = ct * 16 + c;
          float z = sigm(acc[rt][ct][j]);
          if (col < 100){
            pa += z * b2f(X[rloc * XSTR + col]);    // zeta * S/S0
            pg += z * b2f(q[rloc * QSTR + col]);    // zeta * (S/S0)*f
          }
        }
        pa += __shfl_xor(pa, 1, 64); pg += __shfl_xor(pg, 1, 64);
        pa += __shfl_xor(pa, 2, 64); pg += __shfl_xor(pg, 2, 64);
        pa += __shfl_xor(pa, 4, 64); pg += __shfl_xor(pg, 4, 64);
        pa += __shfl_xor(pa, 8, 64); pg += __shfl_xor(pg, 8, 64);
        if (c == 0) cbuf[row0 + rloc] = 100.f * (pg - 0.001f * pa);  // g - R*DT*a
      }
    }
  };

  // ---- layer 1 (A from global X, both halves prefetched) ----
  short8 a1[2][2][4];
  #pragma unroll
  for (int p = 0; p < 2; ++p)
    #pragma unroll
    for (int rt = 0; rt < 2; ++rt){
      const unsigned short* xr = X + (waveRow + p * 32 + rt * 16 + c) * XSTR + g * 8;
      #pragma unroll
      for (int ks = 0; ks < 4; ++ks) a1[p][rt][ks] = *(const short8*)(xr + ks * 32);
    }
  {
    float bv[8], gv[8], bev[8];
    #pragma unroll
    for (int ct = 0; ct < 8; ++ct){ bv[ct] = b1[ct*16+c]; gv[ct] = g1[ct*16+c]; bev[ct] = be1[ct*16+c]; }
    dense_ln(0, a1[0], wbuf0, bv, gv, bev);
    dense_ln(1, a1[1], wbuf0, bv, gv, bev);
  }
  write_stage(wbuf1);          // WT2
  __syncthreads();
  prefetch(WT + 32768);        // WT3
  {
    float bv[8], gv[8], bev[8];
    #pragma unroll
    for (int ct = 0; ct < 8; ++ct){ bv[ct] = b2[ct*16+c]; gv[ct] = g2[ct*16+c]; bev[ct] = be2[ct*16+c]; }
    short8 af[2][4];
    load_afH(0, af); dense_ln(0, af, wbuf1, bv, gv, bev);
    load_afH(1, af); dense_ln(1, af, wbuf1, bv, gv, bev);
  }
  write_stage(wbuf0);          // WT3
  __syncthreads();
  prefetch(WT + 49152);        // WT4
  {
    float bv[8], gv[8], bev[8];
    #pragma unroll
    for (int ct = 0; ct < 8; ++ct){ bv[ct] = b3[ct*16+c]; gv[ct] = g3[ct*16+c]; bev[ct] = be3[ct*16+c]; }
    short8 af[2][4];
    load_afH(0, af); dense_ln(0, af, wbuf0, bv, gv, bev);
    load_afH(1, af); dense_ln(1, af, wbuf0, bv, gv, bev);
  }
  write_stage(wbuf1);          // WT4
  __syncthreads();
  {
    float bv4[7];
    #pragma unroll
    for (int ct = 0; ct < 7; ++ct){ int col = ct*16+c; bv4[ct] = (col < 100) ? b4[col] : 0.f; }
    short8 af[2][4];
    load_afH(0, af); dense_out(0, af, wbuf1, bv4);
    load_afH(1, af); dense_out(1, af, wbuf1, bv4);
  }
}

// ---------------- Phase C: affine fold -> Y ----------------
__global__ __launch_bounds__(256) void phaseC(const float* __restrict__ cbuf,
                                              const float* __restrict__ Y0,
                                              float* __restrict__ Yout)
{
  int b = blockIdx.x * 256 + threadIdx.x;
  if (b >= NPATH) return;
  const float kk = 1.0f + 0.05f * (1.0f / 50.0f);   // 1 + R*DT
  float y = Y0[0];
  const float* cb = cbuf + (long)b * NSTEP;
  #pragma unroll 10
  for (int i = 0; i < NSTEP; ++i) y = y * kk + cb[i];
  Yout[b] = y;
}

extern "C" void kernel_launch(void* const* d_in, const int* in_sizes, int n_in,
                              void* d_out, int out_size, void* d_ws, size_t ws_size,
                              hipStream_t stream)
{
  const float* dw  = (const float*)d_in[0];
  const float* tg  = (const float*)d_in[1];
  const float* W1  = (const float*)d_in[2];
  const float* b1  = (const float*)d_in[3];
  const float* g1  = (const float*)d_in[4];
  const float* be1 = (const float*)d_in[5];
  const float* W2  = (const float*)d_in[6];
  const float* b2  = (const float*)d_in[7];
  const float* g2  = (const float*)d_in[8];
  const float* be2 = (const float*)d_in[9];
  const float* W3  = (const float*)d_in[10];
  const float* b3  = (const float*)d_in[11];
  const float* g3  = (const float*)d_in[12];
  const float* be3 = (const float*)d_in[13];
  const float* W4  = (const float*)d_in[14];
  const float* b4  = (const float*)d_in[15];
  const float* Y0  = (const float*)d_in[16];
  float* out = (float*)d_out;               // [0,8192): Y ; [8192, 8192+819200): S

  char* ws = (char*)d_ws;
  unsigned short* WT = (unsigned short*)ws;         // 126976 B
  float* cbuf = (float*)(ws + 126976);              // 409600 * 4 B
  char* chunk = ws + 1765376;                       // X/q chunk region (16B aligned)

  prep_weights<<<248, 256, 0, stream>>>(W1, W2, W3, W4, WT);

  long avail = (long)ws_size - 1765376L;
  long pc = (avail > 0) ? (avail / 23200L) : 0;     // per-path: 12800 (X) + 10400 (q) bytes
  if (pc > 8192) pc = 8192;
  pc -= pc % 128;                                   // keep rows a multiple of 6400 (256-row blocks)
  if (pc < 128) pc = 128;

  for (long p0 = 0; p0 < 8192; p0 += pc){
    long np = 8192 - p0; if (np > pc) np = pc;
    unsigned short* Xc = (unsigned short*)chunk;
    unsigned short* qc = Xc + np * 50L * XSTR;
    phaseA<<<(int)np, 64, 0, stream>>>(dw, tg, Xc, qc, out + 8192, (int)p0);
    long nrows = np * 50L;
    phaseB<<<(int)(nrows / 256), 256, 0, stream>>>(Xc, qc, WT,
        b1, g1, be1, b2, g2, be2, b3, g3, be3, b4, cbuf, p0 * 50L);
  }
  phaseC<<<32, 256, 0, stream>>>(cbuf, Y0, out);
}

// Round 2
// 260.517 us; speedup vs baseline: 2.1438x; 2.1438x over previous
//
#include <hip/hip_runtime.h>
#include <hip/hip_bf16.h>
#include <cstdint>
#include <cstddef>

typedef __attribute__((ext_vector_type(8))) short short8;
typedef __attribute__((ext_vector_type(4))) float f32x4;

#define NDIM 100
#define NSTEP 50
#define NPATH 8192
#define XSTR 128   // X row stride (elems): [S/S0 (100), t (1), zeros (27)]
#define ESTR 104   // E row stride (elems): e = 0.2*S*w  (c_i = sum zeta*e)

typedef const __attribute__((address_space(1))) unsigned int glb_u32;
typedef __attribute__((address_space(3))) unsigned int lds_u32;

__device__ __forceinline__ unsigned short f2b(float f){
  unsigned int u = __float_as_uint(f);
  u += 0x7fffu + ((u >> 16) & 1u);          // RNE
  return (unsigned short)(u >> 16);
}
__device__ __forceinline__ float b2f(unsigned short h){
  return __uint_as_float(((unsigned int)h) << 16);
}
__device__ __forceinline__ float sigm(float x){
  return __builtin_amdgcn_rcpf(1.f + __expf(-x));
}

// ---------------- weight prep: transpose to [n][k] bf16, zero-padded to 128x128 each ----------------
// WT elems: WT1 @0 ; WT2 @16384 ; WT3 @32768 ; WT4 @49152  (each [128n][128k])
__global__ __launch_bounds__(256) void prep_weights(
    const float* __restrict__ W1, const float* __restrict__ W2,
    const float* __restrict__ W3, const float* __restrict__ W4,
    unsigned short* __restrict__ WT)
{
  int idx = blockIdx.x * 256 + threadIdx.x;   // grid covers exactly 65536
  int seg = idx >> 14;
  int t = idx & 16383;
  int n = t >> 7, k = t & 127;
  float v;
  if (seg == 0)      v = (k <= NDIM) ? W1[k * 128 + n] : 0.f;
  else if (seg == 1) v = W2[k * 128 + n];
  else if (seg == 2) v = W3[k * 128 + n];
  else               v = (n < NDIM) ? W4[k * NDIM + n] : 0.f;
  WT[idx] = f2b(v);
}

// ---------------- Phase A: S-chain scan, emit X (net input) / E (=0.2*S*w) / final S ----------------
__global__ __launch_bounds__(64) void phaseA(
    const float* __restrict__ dw, const float* __restrict__ tg,
    unsigned short* __restrict__ X, unsigned short* __restrict__ E,
    float* __restrict__ Sout, int path0)
{
  const int bl = blockIdx.x;
  const int b  = path0 + bl;
  const int t  = threadIdx.x;
  const int d0 = t, d1 = t + 64;
  float s0 = 100.f, s1 = 100.f;
  const float* dwb = dw + (long)b * NSTEP * NDIM;
  const float* tgb = tg + (long)b * NSTEP;
  unsigned short* Xb = X + (long)bl * NSTEP * XSTR;
  unsigned short* Eb = E + (long)bl * NSTEP * ESTR;
  for (int i = 0; i < NSTEP; ++i){
    float tv = tgb[i];
    float w0 = dwb[i * NDIM + d0];
    float w1 = (d1 < NDIM) ? dwb[i * NDIM + d1] : 0.f;
    unsigned short* Xr = Xb + i * XSTR;
    unsigned short* Er = Eb + i * ESTR;
    Xr[d0] = f2b(s0 * 0.01f);
    Er[d0] = f2b(0.2f * s0 * w0);
    if (d1 < NDIM){ Xr[d1] = f2b(s1 * 0.01f); Er[d1] = f2b(0.2f * s1 * w1); }
    else if (d1 == NDIM){ Xr[d1] = f2b(tv); }
    else { Xr[d1] = 0; }
    s0 += s0 * (0.001f + 0.2f * w0);
    if (d1 < NDIM) s1 += s1 * (0.001f + 0.2f * w1);
  }
  Sout[(long)b * NDIM + d0] = s0;
  if (d1 < NDIM) Sout[(long)b * NDIM + d1] = s1;
}

// ---------------- Phase B: fused 4-layer MLP, 16 rows/wave, 64 rows/block ----------------
// LDS 49152 B -> 3 blocks/CU (12 waves/CU). Weight buffer [128][256B] XOR-swizzled
// (slot ^= row&7) staged via global_load_lds with pre-swizzled SOURCE (linear dest).
// H per-wave [16][256B], same swizzle, written b16 / read b128.
// MFMA 16x16x32 bf16: A row=lane&15 k=(lane>>4)*8+j ; C/D col=lane&15 row=4*(lane>>4)+reg.
__global__ __launch_bounds__(256, 3) void phaseB(
    const unsigned short* __restrict__ X,
    const unsigned short* __restrict__ E,
    const unsigned short* __restrict__ WT,
    const float* __restrict__ b1, const float* __restrict__ g1, const float* __restrict__ be1,
    const float* __restrict__ b2, const float* __restrict__ g2, const float* __restrict__ be2,
    const float* __restrict__ b3, const float* __restrict__ g3, const float* __restrict__ be3,
    const float* __restrict__ b4,
    float* __restrict__ cbuf, long row0)
{
  __shared__ __align__(16) char lds[49152];
  char* const wbuf = lds;                         // 32768 B weights
  const int tid = threadIdx.x;
  const int w = tid >> 6;
  const int l = tid & 63;
  const int g = l >> 4;
  const int c = l & 15;
  char* const H = lds + 32768 + w * 4096;         // per-wave 16 rows x 256 B
  const long waveRow = (long)blockIdx.x * 64 + w * 16;
  const int c7x = (c & 7) << 4;                   // read-side swizzle XOR (byte addr)

  // stage one 128x128 bf16 weight tile; LDS[row][slot] = WT[row][slot ^ (row&7)] (16B slots)
  auto stage = [&](int woff){
    #pragma unroll
    for (int it = 0; it < 8; ++it){
      int cl = (w * 8 + it) * 64 + l;             // 16B-chunk id 0..2047
      int row = cl >> 4, slot = cl & 15;
      const unsigned short* src = WT + woff + row * 128 + ((slot ^ (row & 7)) << 3);
      __builtin_amdgcn_global_load_lds((glb_u32*)src,
          (lds_u32*)(wbuf + (w * 8 + it) * 1024), 16, 0, 0);
    }
  };

  short8 af[4];
  auto load_af_X = [&](){                         // layer-1 A-frags from global X
    const unsigned short* xr = X + (waveRow + c) * XSTR + g * 8;
    #pragma unroll
    for (int ks = 0; ks < 4; ++ks) af[ks] = *(const short8*)(xr + ks * 32);
  };
  auto load_af_H = [&](){
    const char* hr = H + (c << 8);
    #pragma unroll
    for (int ks = 0; ks < 4; ++ks)
      af[ks] = *(const short8*)(hr + ((64 * ks + 16 * g) ^ c7x));
  };

  // dense + LayerNorm + GELU -> H  (layers 1..3)
  auto dense_ln = [&](const float* bv_, const float* gv_, const float* bev_){
    float bvv[8], gvv[8], bevv[8];
    #pragma unroll
    for (int ct = 0; ct < 8; ++ct){
      bvv[ct] = bv_[ct * 16 + c]; gvv[ct] = gv_[ct * 16 + c]; bevv[ct] = bev_[ct * 16 + c];
    }
    f32x4 acc[8];
    #pragma unroll
    for (int ct = 0; ct < 8; ++ct){
      f32x4 z; z[0] = bvv[ct]; z[1] = bvv[ct]; z[2] = bvv[ct]; z[3] = bvv[ct];
      acc[ct] = z;
    }
    #pragma unroll
    for (int ct = 0; ct < 8; ++ct){
      const char* rowp = wbuf + ((ct * 16 + c) << 8);
      #pragma unroll
      for (int ks = 0; ks < 4; ++ks){
        short8 bf = *(const short8*)(rowp + ((64 * ks + 16 * g) ^ c7x));
        acc[ct] = __builtin_amdgcn_mfma_f32_16x16x32_bf16(af[ks], bf, acc[ct], 0, 0, 0);
      }
    }
    #pragma unroll
    for (int j = 0; j < 4; ++j){
      float s1 = 0.f, s2 = 0.f;
      #pragma unroll
      for (int ct = 0; ct < 8; ++ct){ float x = acc[ct][j]; s1 += x; s2 += x * x; }
      s1 += __shfl_xor(s1, 1, 64); s2 += __shfl_xor(s2, 1, 64);
      s1 += __shfl_xor(s1, 2, 64); s2 += __shfl_xor(s2, 2, 64);
      s1 += __shfl_xor(s1, 4, 64); s2 += __shfl_xor(s2, 4, 64);
      s1 += __shfl_xor(s1, 8, 64); s2 += __shfl_xor(s2, 8, 64);
      float mu = s1 * 0.0078125f;
      float rstd = rsqrtf(s2 * 0.0078125f - mu * mu + 1e-5f);
      int row = 4 * g + j;
      char* hw = H + (row << 8);
      int sw = (row & 7) << 4;
      #pragma unroll
      for (int ct = 0; ct < 8; ++ct){
        float y = (acc[ct][j] - mu) * rstd * gvv[ct] + bevv[ct];
        float h = y * sigm(1.702f * y);
        *(unsigned short*)(hw + ((ct * 32 + 2 * c) ^ sw)) = f2b(h);
      }
    }
  };

  // layer 4: dense + sigmoid + epilogue reduce -> cbuf
  auto dense_out = [&](){
    float bv4[7];
    #pragma unroll
    for (int ct = 0; ct < 7; ++ct){
      int col = ct * 16 + c;
      bv4[ct] = (col < NDIM) ? b4[col] : 0.f;
    }
    f32x4 acc[7];
    #pragma unroll
    for (int ct = 0; ct < 7; ++ct){
      f32x4 z; z[0] = bv4[ct]; z[1] = bv4[ct]; z[2] = bv4[ct]; z[3] = bv4[ct];
      acc[ct] = z;
    }
    #pragma unroll
    for (int ct = 0; ct < 7; ++ct){
      const char* rowp = wbuf + ((ct * 16 + c) << 8);
      #pragma unroll
      for (int ks = 0; ks < 4; ++ks){
        short8 bf = *(const short8*)(rowp + ((64 * ks + 16 * g) ^ c7x));
        acc[ct] = __builtin_amdgcn_mfma_f32_16x16x32_bf16(af[ks], bf, acc[ct], 0, 0, 0);
      }
    }
    #pragma unroll
    for (int j = 0; j < 4; ++j){
      long rloc = waveRow + 4 * g + j;
      float pg = 0.f;
      #pragma unroll
      for (int ct = 0; ct < 7; ++ct){
        int col = ct * 16 + c;
        float z = sigm(acc[ct][j]);
        if (col < NDIM) pg += z * b2f(E[rloc * ESTR + col]);   // zeta * 0.2*S*w
      }
      pg += __shfl_xor(pg, 1, 64);
      pg += __shfl_xor(pg, 2, 64);
      pg += __shfl_xor(pg, 4, 64);
      pg += __shfl_xor(pg, 8, 64);
      if (c == 0) cbuf[row0 + rloc] = pg;
    }
  };

  stage(0);
  __syncthreads();
  load_af_X();  dense_ln(b1, g1, be1);
  __syncthreads();  stage(16384);  __syncthreads();
  load_af_H();  dense_ln(b2, g2, be2);
  __syncthreads();  stage(32768);  __syncthreads();
  load_af_H();  dense_ln(b3, g3, be3);
  __syncthreads();  stage(49152);  __syncthreads();
  load_af_H();  dense_out();
}

// ---------------- Phase C: affine fold -> Y ----------------
__global__ __launch_bounds__(256) void phaseC(const float* __restrict__ cbuf,
                                              const float* __restrict__ Y0,
                                              float* __restrict__ Yout)
{
  int b = blockIdx.x * 256 + threadIdx.x;
  if (b >= NPATH) return;
  const float kk = 1.0f + 0.05f * (1.0f / 50.0f);   // 1 + R*DT
  float y = Y0[0];
  const float* cb = cbuf + (long)b * NSTEP;
  #pragma unroll 10
  for (int i = 0; i < NSTEP; ++i) y = y * kk + cb[i];
  Yout[b] = y;
}

extern "C" void kernel_launch(void* const* d_in, const int* in_sizes, int n_in,
                              void* d_out, int out_size, void* d_ws, size_t ws_size,
                              hipStream_t stream)
{
  const float* dw  = (const float*)d_in[0];
  const float* tg  = (const float*)d_in[1];
  const float* W1  = (const float*)d_in[2];
  const float* b1  = (const float*)d_in[3];
  const float* g1  = (const float*)d_in[4];
  const float* be1 = (const float*)d_in[5];
  const float* W2  = (const float*)d_in[6];
  const float* b2  = (const float*)d_in[7];
  const float* g2  = (const float*)d_in[8];
  const float* be2 = (const float*)d_in[9];
  const float* W3  = (const float*)d_in[10];
  const float* b3  = (const float*)d_in[11];
  const float* g3  = (const float*)d_in[12];
  const float* be3 = (const float*)d_in[13];
  const float* W4  = (const float*)d_in[14];
  const float* b4  = (const float*)d_in[15];
  const float* Y0  = (const float*)d_in[16];
  float* out = (float*)d_out;               // [0,8192): Y ; [8192,8192+819200): S

  char* ws = (char*)d_ws;
  unsigned short* WT = (unsigned short*)ws;         // 131072 B
  float* cbuf = (float*)(ws + 131072);              // 409600 * 4 B
  char* chunk = ws + 1769472;                       // X/E chunk region (16B aligned)

  prep_weights<<<256, 256, 0, stream>>>(W1, W2, W3, W4, WT);

  long avail = (long)ws_size - 1769472L;
  long pc = (avail > 0) ? (avail / 23200L) : 0;     // per-path: 12800 (X) + 10400 (E) B
  if (pc > 8192) pc = 8192;
  pc -= pc % 128;                                   // rows stay multiple of 64
  if (pc < 128) pc = 128;

  for (long p0 = 0; p0 < 8192; p0 += pc){
    long np = 8192 - p0; if (np > pc) np = pc;
    unsigned short* Xc = (unsigned short*)chunk;
    unsigned short* Ec = Xc + np * 50L * XSTR;
    phaseA<<<(int)np, 64, 0, stream>>>(dw, tg, Xc, Ec, out + 8192, (int)p0);
    long nrows = np * 50L;
    phaseB<<<(int)(nrows / 64), 256, 0, stream>>>(Xc, Ec, WT,
        b1, g1, be1, b2, g2, be2, b3, g3, be3, b4, cbuf, p0 * 50L);
  }
  phaseC<<<32, 256, 0, stream>>>(cbuf, Y0, out);
}